// Round 9
// baseline (34375.851 us; speedup 1.0000x reference)
//
#include <hip/hip_runtime.h>

#define Bz 32
#define Tz 512
#define Dz 512
#define Lz 1024
#define Mz 10
#define G4D 2048
#define KTOT 1536            // [x_t ; ctx ; h]
#define NK2 768              // KTOT/2 packed f16 pairs
#define KC 128

typedef _Float16 half2_t __attribute__((ext_vector_type(2)));

#if defined(__has_builtin)
#if __has_builtin(__builtin_amdgcn_fdot2)
#define HAS_FDOT2 1
#endif
#endif

__device__ __forceinline__ float fsig(float x) { return 1.0f / (1.0f + __expf(-x)); }
__device__ __forceinline__ int ld_rlx(const int* p) {
  return __hip_atomic_load(p, __ATOMIC_RELAXED, __HIP_MEMORY_SCOPE_AGENT);
}
__device__ __forceinline__ void add_rlx(int* p) {
  (void)__hip_atomic_fetch_add(p, 1, __ATOMIC_RELAXED, __HIP_MEMORY_SCOPE_AGENT);
}
__device__ __forceinline__ unsigned pack16(float a, float b) {
  unsigned short la = __builtin_bit_cast(unsigned short, (_Float16)a);
  unsigned short lb = __builtin_bit_cast(unsigned short, (_Float16)b);
  return (unsigned)la | ((unsigned)lb << 16);
}
__device__ __forceinline__ float dot2f(unsigned xu, unsigned wu, float acc) {
  half2_t xh = __builtin_bit_cast(half2_t, xu);
  half2_t wh = __builtin_bit_cast(half2_t, wu);
#ifdef HAS_FDOT2
  return __builtin_amdgcn_fdot2(xh, wh, acc, false);
#else
  return acc + (float)xh[0]*(float)wh[0] + (float)xh[1]*(float)wh[1];
#endif
}

// ---------------- K0 (once): pack W into f16-pair, k-major layout ----------------
// Wp[s][j] = pack( W(j,2s), W(j,2s+1) ), s in [0,768), j in [0,2048)
// W(j,kk) = kk<1024 ? W_ih[j][kk] : W_hh[j][kk-1024]   (x cols 0..511, ctx 512..1023, h 1024..1535)
__global__ __launch_bounds__(256) void k_pack(
    const float* __restrict__ W_ih, const float* __restrict__ W_hh,
    unsigned* __restrict__ Wp)
{
  const int s = blockIdx.x;
  const int kk = 2*s;
  for (int j = threadIdx.x; j < G4D; j += 256) {
    float w0, w1;
    if (kk < 1024) {
      w0 = W_ih[(size_t)j*1024 + kk];
      w1 = W_ih[(size_t)j*1024 + kk + 1];
    } else {
      w0 = W_hh[(size_t)j*512 + kk - 1024];
      w1 = W_hh[(size_t)j*512 + kk - 1023];
    }
    Wp[(size_t)s*G4D + j] = pack16(w0, w1);
  }
}

// ---------------- Main: one self-contained block per batch, all 512 steps ----------------
// No cross-block data flow. State (c,h,ctx) lives in LDS. Weights streamed f16 from
// L2/MALL each step. Epoch-gate counter keeps blocks lockstep for L2 stream sharing.
__global__ __launch_bounds__(1024, 1) void k_batch(
    const float* __restrict__ x, const float* __restrict__ memory,
    const int* __restrict__ lens,
    const float* __restrict__ b_ih, const float* __restrict__ b_hh,
    const float* __restrict__ W_g,  const float* __restrict__ b_g,
    const unsigned* __restrict__ Wp, int* __restrict__ cnt,
    float* __restrict__ ctx_out, float* __restrict__ align_out,
    float* __restrict__ term_out)
{
  const int b = blockIdx.x, tid = threadIdx.x;

  __shared__ float bsum[G4D];      // b_ih + b_hh (8 KB, loaded once)
  __shared__ unsigned xp[NK2];     // packed f16 x-hat (3 KB)
  __shared__ float gp0[G4D];       // gates partial kh=0 (8 KB)
  __shared__ float gp1[G4D];       // gates partial kh=1 (8 KB); overlaid by einsum partials
  __shared__ float cs[Dz], hs[Dz], ctxl[Dz];
  __shared__ float wsm[Lz];
  __shared__ float phis[3*Mz], prm[3*Mz], lom[Mz], him[Mz];
  __shared__ int   rng[2];
  float (*part)[Dz] = reinterpret_cast<float(*)[Dz]>(gp1);   // einsum partials

  for (int j = tid; j < G4D; j += 1024) bsum[j] = b_ih[j] + b_hh[j];
  if (tid < Dz) { cs[tid] = 0.f; hs[tid] = 0.f; ctxl[tid] = 0.f; }
  __syncthreads();

  // GEMM thread mapping: kh = K-half, jq -> 4 consecutive j columns
  const int kh = tid >> 9, jq = tid & 511;
  const int j0 = jq << 2;

  for (int t = 0; t < Tz; ++t) {
    // ---- epoch gate: rendezvous so same-XCD blocks share the Wp stream in L2
    if (t > 0 && tid == 0) {
      const int tgt = Bz * t;
      while (ld_rlx(cnt) < tgt) __builtin_amdgcn_s_sleep(1);
    }
    __syncthreads();

    // ---- stage x-hat = [x_t ; ctx ; h] as packed f16 pairs
    if (tid < NK2) {
      const int s = tid;
      float v0, v1;
      if (s < 256) {
        float2 xv = *reinterpret_cast<const float2*>(&x[((size_t)b*Tz + t)*Dz + 2*s]);
        v0 = xv.x; v1 = xv.y;
      } else if (s < 512) {
        v0 = ctxl[2*s - 512]; v1 = ctxl[2*s - 511];
      } else {
        v0 = hs[2*s - 1024]; v1 = hs[2*s - 1023];
      }
      xp[s] = pack16(v0, v1);
    }
    __syncthreads();

    // ---- gates GEMM: 384 k2-iters per thread, 4 j columns, f16 dot2, f32 accum
    {
      float a0 = 0.f, a1 = 0.f, a2 = 0.f, a3 = 0.f;
      const uint4* wp4 = reinterpret_cast<const uint4*>(Wp) + (size_t)(kh*384)*512 + jq;
      const unsigned* xk = xp + kh*384;
      #pragma unroll 4
      for (int i = 0; i < 384; i++) {
        uint4 w = wp4[(size_t)i*512];
        unsigned xv = xk[i];
        a0 = dot2f(xv, w.x, a0);
        a1 = dot2f(xv, w.y, a1);
        a2 = dot2f(xv, w.z, a2);
        a3 = dot2f(xv, w.w, a3);
      }
      float* gp = kh ? gp1 : gp0;
      gp[j0] = a0; gp[j0+1] = a1; gp[j0+2] = a2; gp[j0+3] = a3;
    }
    __syncthreads();

    // ---- LSTM pointwise (d = tid < 512); gate order i,f,g,o
    if (tid < Dz) {
      const int d = tid;
      float gi = gp0[d]        + gp1[d]        + bsum[d];
      float gf = gp0[Dz+d]     + gp1[Dz+d]     + bsum[Dz+d];
      float gg = gp0[2*Dz+d]   + gp1[2*Dz+d]   + bsum[2*Dz+d];
      float go = gp0[3*Dz+d]   + gp1[3*Dz+d]   + bsum[3*Dz+d];
      float ig = 1.0f/(1.0f+expf(-gi));
      float fg = 1.0f/(1.0f+expf(-gf));
      float g2 = tanhf(gg);
      float og = 1.0f/(1.0f+expf(-go));
      float cn = fg*cs[d] + ig*g2;
      float hn = og*tanhf(cn);
      cs[d] = cn; hs[d] = hn;
    }
    __syncthreads();

    // ---- phi[m] = hs . W_g[m,:] + b_g[m]  (32 lanes per m, 30 m)
    if (tid < 32*3*Mz) {
      const int m = tid >> 5, ln = tid & 31;
      float s = 0.f;
      #pragma unroll 4
      for (int k = ln; k < Dz; k += 32) s += W_g[m*Dz + k] * hs[k];
      s += __shfl_xor(s, 1);
      s += __shfl_xor(s, 2);
      s += __shfl_xor(s, 4);
      s += __shfl_xor(s, 8);
      s += __shfl_xor(s, 16);
      if (ln == 0) phis[m] = s + b_g[m];
    }
    __syncthreads();

    // ---- GMM params + active l-range
    if (tid < Mz) {
      float ks = expf(phis[tid]);
      float be = expf(phis[Mz + tid]);
      prm[tid]      = ks;
      prm[Mz + tid] = expf(-phis[Mz + tid]);   // 1/beta
      lom[tid] = ks - 0.5f - 25.f*be;          // sig(-25) below fp32 visibility
      him[tid] = ks + 0.5f + 25.f*be;
    }
    __syncthreads();
    if (tid == 0) {
      float mx = -1e30f;
      #pragma unroll
      for (int m = 0; m < Mz; m++) mx = fmaxf(mx, phis[2*Mz + m]);
      float ae[Mz], ssum = 0.f;
      #pragma unroll
      for (int m = 0; m < Mz; m++) { ae[m] = expf(phis[2*Mz + m] - mx); ssum += ae[m]; }
      float lo = 1e30f, hi = -1e30f;
      #pragma unroll
      for (int m = 0; m < Mz; m++) {
        prm[2*Mz + m] = ae[m] / ssum;
        lo = fminf(lo, lom[m]); hi = fmaxf(hi, him[m]);
      }
      int llo = lo > 0.f ? (int)floorf(lo) : 0;
      if (llo > Lz) llo = Lz;
      int lhi = hi < (float)Lz ? (int)ceilf(hi) + 1 : Lz;
      if (lhi > Lz) lhi = Lz;
      rng[0] = llo; rng[1] = lhi;
    }
    __syncthreads();
    const int llo = rng[0], lhi = rng[1];

    // ---- w on active range
    for (int l = llo + tid; l < lhi; l += 1024) {
      float u = (float)l;
      float t1 = 0.f, t0 = 0.f;
      #pragma unroll
      for (int m = 0; m < Mz; m++) {
        float ks = prm[m], ib = prm[Mz + m], al = prm[2*Mz + m];
        t1 += al * fsig((u + 0.5f - ks) * ib);
        t0 += al * fsig((u - 0.5f - ks) * ib);
      }
      wsm[l] = t1 - t0;
    }
    __syncthreads();

    // ---- ctx einsum: 2 l-segments x 512 d (gp1 dead -> partials)
    {
      const int seg = tid >> 9, d = tid & 511;
      const float* mb = memory + (size_t)b*Lz*Dz + d;
      float a = 0.f;
      for (int l = llo + seg; l < lhi; l += 2)
        a = fmaf(wsm[l], mb[(size_t)l*Dz], a);
      part[seg][d] = a;
    }
    __syncthreads();
    if (tid < Dz) {
      float s = part[0][tid] + part[1][tid];
      ctxl[tid] = s;
      if (t == Tz-1) ctx_out[b*Dz + tid] = s;
    }
    // alignment row (inactive range pre-zeroed once per call)
    for (int l = llo + tid; l < lhi; l += 1024)
      align_out[((size_t)b*Tz + t)*Lz + l] = wsm[l];
    if (t == Tz-1 && tid == 0) {
      float u = (float)(lens[b] - 1);
      float t1 = 0.f;
      #pragma unroll
      for (int m = 0; m < Mz; m++)
        t1 += prm[2*Mz + m] * fsig((u + 0.5f - prm[m]) * prm[Mz + m]);
      term_out[b] = 1.0f - t1;
    }
    __syncthreads();
    if (tid == 0) add_rlx(cnt);
  }
}

// ================= fallback (small ws): two-kernel loop path =================
__global__ __launch_bounds__(256) void k_gemm(
    const float* __restrict__ x_all, const float* __restrict__ ctxs,
    const float* __restrict__ h, const float* __restrict__ W_ih,
    const float* __restrict__ W_hh, float* __restrict__ partial, int t)
{
  __shared__ float Xs[Bz][KC+2];
  __shared__ float Wt[128][KC+2];
  const int jt = blockIdx.x, kcb = blockIdx.y;
  const int j0 = jt*128, k0 = kcb*KC;
  const int tid = threadIdx.x;
  for (int i = tid; i < Bz*KC; i += 256) {
    int bb = i >> 7, kk = i & (KC-1);
    int k = k0 + kk;
    float v;
    if (k < Dz)        v = x_all[((size_t)bb*Tz + t)*Dz + k];
    else if (k < 2*Dz) v = ctxs[bb*Dz + (k - Dz)];
    else               v = h[bb*Dz + (k - 2*Dz)];
    Xs[bb][kk] = v;
  }
  {
    const float* Wsrc; int ldw, col0;
    if (k0 < 2*Dz) { Wsrc = W_ih; ldw = 2*Dz; col0 = k0; }
    else           { Wsrc = W_hh; ldw = Dz;   col0 = k0 - 2*Dz; }
    for (int i = tid; i < 128*(KC/4); i += 256) {
      int jj = i >> 5, k4 = (i & 31) << 2;
      float4 v = *reinterpret_cast<const float4*>(&Wsrc[(size_t)(j0 + jj)*ldw + col0 + k4]);
      Wt[jj][k4] = v.x; Wt[jj][k4+1] = v.y; Wt[jj][k4+2] = v.z; Wt[jj][k4+3] = v.w;
    }
  }
  __syncthreads();
  const int jg = tid & 31, bg = tid >> 5;
  const int bl = bg << 2;
  float acc[4][4] = {};
  #pragma unroll 4
  for (int k = 0; k < KC; k += 2) {
    float2 xv[4], wv[4];
    #pragma unroll
    for (int bb2 = 0; bb2 < 4; bb2++)
      xv[bb2] = *reinterpret_cast<const float2*>(&Xs[bl + bb2][k]);
    #pragma unroll
    for (int jj = 0; jj < 4; jj++)
      wv[jj] = *reinterpret_cast<const float2*>(&Wt[jg + (jj << 5)][k]);
    #pragma unroll
    for (int jj = 0; jj < 4; jj++)
      #pragma unroll
      for (int bb2 = 0; bb2 < 4; bb2++)
        acc[jj][bb2] += wv[jj].x * xv[bb2].x + wv[jj].y * xv[bb2].y;
  }
  #pragma unroll
  for (int jj = 0; jj < 4; jj++)
    #pragma unroll
    for (int bb2 = 0; bb2 < 4; bb2++)
      partial[((size_t)kcb*Bz + (bl + bb2))*G4D + j0 + jg + (jj << 5)] = acc[jj][bb2];
}

__global__ __launch_bounds__(512) void k_fused(
    const float* __restrict__ partial, const float* __restrict__ b_ih,
    const float* __restrict__ b_hh,
    float* __restrict__ h, float* __restrict__ c,
    const float* __restrict__ W_g, const float* __restrict__ b_g,
    const float* __restrict__ memory, const int* __restrict__ lens,
    float* __restrict__ ctxs, float* __restrict__ ctx_out,
    float* __restrict__ align_out, float* __restrict__ term_out,
    int t, int final_, int nkc)
{
  const int b = blockIdx.x, tid = threadIdx.x;
  __shared__ float4 gs4[G4D/4];
  __shared__ float hsb[Dz];
  __shared__ float phis[3*Mz];
  __shared__ float prm[3*Mz];
  __shared__ float wsm[Lz];
  __shared__ int   rng[2];
  float* gs = (float*)gs4;
  {
    int j = 4*tid;
    float4 bi = *reinterpret_cast<const float4*>(&b_ih[j]);
    float4 bh = *reinterpret_cast<const float4*>(&b_hh[j]);
    float4 s = make_float4(bi.x+bh.x, bi.y+bh.y, bi.z+bh.z, bi.w+bh.w);
    const float4* pp = reinterpret_cast<const float4*>(partial) + (size_t)b*(G4D/4) + tid;
    for (int kcb = 0; kcb < nkc; kcb++) {
      float4 p = pp[(size_t)kcb*Bz*(G4D/4)];
      s.x += p.x; s.y += p.y; s.z += p.z; s.w += p.w;
    }
    gs4[tid] = s;
  }
  __syncthreads();
  {
    const int d = tid;
    float ig = 1.0f / (1.0f + expf(-gs[d]));
    float fg = 1.0f / (1.0f + expf(-gs[Dz + d]));
    float gg = tanhf(gs[2*Dz + d]);
    float og = 1.0f / (1.0f + expf(-gs[3*Dz + d]));
    float cn = fg * c[b*Dz + d] + ig * gg;
    float hn = og * tanhf(cn);
    c[b*Dz + d] = cn;
    h[b*Dz + d] = hn;
    hsb[d] = hn;
  }
  __syncthreads();
  if (tid < 16*3*Mz) {
    int m = tid >> 4, l16 = tid & 15;
    float s = 0.f;
    #pragma unroll 4
    for (int k = l16; k < Dz; k += 16) s += W_g[m*Dz + k] * hsb[k];
    s += __shfl_xor(s, 1);
    s += __shfl_xor(s, 2);
    s += __shfl_xor(s, 4);
    s += __shfl_xor(s, 8);
    if (l16 == 0) phis[m] = s + b_g[m];
  }
  __syncthreads();
  if (tid == 0) {
    float mx = -1e30f;
    #pragma unroll
    for (int m = 0; m < Mz; m++) mx = fmaxf(mx, phis[2*Mz + m]);
    float ae[Mz], ssum = 0.f;
    #pragma unroll
    for (int m = 0; m < Mz; m++) { ae[m] = expf(phis[2*Mz + m] - mx); ssum += ae[m]; }
    float lo = 1e30f, hi = -1e30f;
    #pragma unroll
    for (int m = 0; m < Mz; m++) {
      float ks = expf(phis[m]);
      float be = expf(phis[Mz + m]);
      prm[m]        = ks;
      prm[Mz + m]   = expf(-phis[Mz + m]);
      prm[2*Mz + m] = ae[m] / ssum;
      lo = fminf(lo, ks - 0.5f - 25.f*be);
      hi = fmaxf(hi, ks + 0.5f + 25.f*be);
    }
    int llo = lo > 0.f ? (int)floorf(lo) : 0;
    if (llo > Lz) llo = Lz;
    int lhi = hi < (float)Lz ? (int)ceilf(hi) + 1 : Lz;
    if (lhi > Lz) lhi = Lz;
    rng[0] = llo; rng[1] = lhi;
  }
  __syncthreads();
  const int llo = rng[0], lhi = rng[1];
  for (int l = llo + tid; l < lhi; l += 512) {
    float u = (float)l;
    float t1 = 0.f, t0 = 0.f;
    #pragma unroll
    for (int m = 0; m < Mz; m++) {
      float ks = prm[m], ib = prm[Mz + m], al = prm[2*Mz + m];
      t1 += al * fsig((u + 0.5f - ks) * ib);
      t0 += al * fsig((u - 0.5f - ks) * ib);
    }
    float w = t1 - t0;
    wsm[l] = w;
    align_out[((size_t)b*Tz + t)*Lz + l] = w;
  }
  __syncthreads();
  {
    const float* mb = memory + (size_t)b*Lz*Dz + tid;
    float acc = 0.f;
    #pragma unroll 4
    for (int l = llo; l < lhi; l++)
      acc += wsm[l] * mb[(size_t)l*Dz];
    ctxs[b*Dz + tid] = acc;
    if (final_) ctx_out[b*Dz + tid] = acc;
  }
  if (final_ && tid == 0) {
    float u = (float)(lens[b] - 1);
    float t1 = 0.f;
    #pragma unroll
    for (int m = 0; m < Mz; m++)
      t1 += prm[2*Mz + m] * fsig((u + 0.5f - prm[m]) * prm[Mz + m]);
    term_out[b] = 1.0f - t1;
  }
}

extern "C" void kernel_launch(void* const* d_in, const int* in_sizes, int n_in,
                              void* d_out, int out_size, void* d_ws, size_t ws_size,
                              hipStream_t stream)
{
  (void)in_sizes; (void)n_in; (void)out_size;
  const float* x    = (const float*)d_in[0];
  const float* mem  = (const float*)d_in[1];
  const int*   lens = (const int*)d_in[2];
  const float* W_ih = (const float*)d_in[3];
  const float* W_hh = (const float*)d_in[4];
  const float* b_ih = (const float*)d_in[5];
  const float* b_hh = (const float*)d_in[6];
  const float* W_g  = (const float*)d_in[7];
  const float* b_g  = (const float*)d_in[8];

  float* out = (float*)d_out;
  float* ctx_out   = out;                                  // [B,1,D]
  float* align_out = out + Bz*Dz;                          // [B,T,L]
  float* term_out  = out + Bz*Dz + (size_t)Bz*Tz*Lz;       // [B,1]

  // main path needs: counter page (4 KB) + Wp f16 pack (6 MB)
  const size_t needP = (size_t)4096 + (size_t)NK2*G4D*sizeof(unsigned);

  hipMemsetAsync(align_out, 0, (size_t)Bz*Tz*Lz*sizeof(float), stream);

  if (ws_size >= needP) {
    int*      cnt = (int*)d_ws;
    unsigned* Wp  = (unsigned*)d_ws + 1024;    // 4 KB offset

    hipMemsetAsync(d_ws, 0, 4096, stream);
    k_pack<<<NK2, 256, 0, stream>>>(W_ih, W_hh, Wp);
    k_batch<<<Bz, 1024, 0, stream>>>(x, mem, lens, b_ih, b_hh, W_g, b_g,
                                     Wp, cnt, ctx_out, align_out, term_out);
  } else {
    float* wsf     = (float*)d_ws;
    float* h       = wsf;
    float* c       = h + Bz*Dz;
    float* ctxs    = c + Bz*Dz;
    float* partial = ctxs + Bz*Dz;               // [12][B][4D]
    hipMemsetAsync(d_ws, 0, (size_t)(3*Bz*Dz)*sizeof(float), stream);
    for (int t = 0; t < Tz; t++) {
      k_gemm<<<dim3(G4D/128, 12), 256, 0, stream>>>(x, ctxs, h, W_ih, W_hh, partial, t);
      k_fused<<<Bz, 512, 0, stream>>>(partial, b_ih, b_hh, h, c, W_g, b_g,
                                      mem, lens, ctxs, ctx_out, align_out, term_out,
                                      t, t == Tz-1, 12);
    }
  }
}

// Round 10
// 7857.648 us; speedup vs baseline: 4.3748x; 4.3748x over previous
//
#include <hip/hip_runtime.h>

#define Bz 32
#define Tz 512
#define Dz 512
#define Lz 1024
#define Mz 10
#define G4D 2048
#define JT 64               // j per A-tile
#define NJT 32              // 2048/64
#define NKC 4               // K=1024 split in 4 chunks of 256
#define KCH 256
#define KU 128              // u32 k-pairs per chunk
#define NBLKA 128           // 32 jt x 4 kc
#define NBLK (NBLKA + Bz)   // 160
#define FP 32               // ints per flag slot (128B padding)
// ws int-region offsets
#define OFF_FLAGA 0
#define OFF_FLAGH (NBLKA*FP)            // 4096
#define OFF_FLAGC (OFF_FLAGH + Bz*FP)   // 5120
#define OFF_HP    6144                  // hp[256][32] u32
#define OFF_CP    (OFF_HP + 8192)       // cp[256][32] u32
#define OFF_PART  (OFF_CP + 8192)       // part[4][32][1024] u32 (f16-pair)
#define OFF_XW    (OFF_PART + 131072)   // xw floats after this
// k_pre tiles
#define PM 128
#define PN 128
#define PK 32

typedef unsigned long long u64;
typedef _Float16 half2_t __attribute__((ext_vector_type(2)));

#if defined(__has_builtin)
#if __has_builtin(__builtin_amdgcn_fdot2)
#define HAS_FDOT2 1
#endif
#endif

__device__ __forceinline__ float fsig(float x) { return 1.0f / (1.0f + __expf(-x)); }
__device__ __forceinline__ int ld_rlx(const int* p) {
  return __hip_atomic_load(p, __ATOMIC_RELAXED, __HIP_MEMORY_SCOPE_AGENT);
}
__device__ __forceinline__ void st_rlx(int* p, int v) {
  __hip_atomic_store(p, v, __ATOMIC_RELAXED, __HIP_MEMORY_SCOPE_AGENT);
}
__device__ __forceinline__ void st_rlxu(unsigned* p, unsigned v) {
  __hip_atomic_store(p, v, __ATOMIC_RELAXED, __HIP_MEMORY_SCOPE_AGENT);
}
__device__ __forceinline__ u64 ld_rlx64(const u64* p) {
  return __hip_atomic_load(p, __ATOMIC_RELAXED, __HIP_MEMORY_SCOPE_AGENT);
}
__device__ __forceinline__ unsigned pack16(float a, float b) {
  unsigned short la = __builtin_bit_cast(unsigned short, (_Float16)a);
  unsigned short lb = __builtin_bit_cast(unsigned short, (_Float16)b);
  return (unsigned)la | ((unsigned)lb << 16);
}
__device__ __forceinline__ float dot2f(unsigned xu, unsigned wu, float acc) {
  half2_t xh = __builtin_bit_cast(half2_t, xu);
  half2_t wh = __builtin_bit_cast(half2_t, wu);
#ifdef HAS_FDOT2
  return __builtin_amdgcn_fdot2(xh, wh, acc, false);
#else
  return acc + (float)xh[0]*(float)wh[0] + (float)xh[1]*(float)wh[1];
#endif
}
#define VWAIT() asm volatile("s_waitcnt vmcnt(0)" ::: "memory")

// ---------------- K0 (once): xw[bt][j] = x[bt,:] . W_ih[j,0:512] + b_ih[j] + b_hh[j] ----------------
__global__ __launch_bounds__(256) void k_pre(
    const float* __restrict__ x, const float* __restrict__ W_ih,
    const float* __restrict__ b_ih, const float* __restrict__ b_hh,
    float* __restrict__ xw)
{
  __shared__ float As[PM][PK+1];
  __shared__ float Bs[PN][PK+1];
  const int m0 = blockIdx.x*PM, n0 = blockIdx.y*PN;
  const int tid = threadIdx.x;
  const int mg = tid >> 4, ng = tid & 15;
  float acc[8][8] = {};
  for (int k0 = 0; k0 < Dz; k0 += PK) {
    for (int i = tid; i < PM*(PK/4); i += 256) {
      int row = i >> 3, c4 = (i & 7) << 2;
      float4 v = *reinterpret_cast<const float4*>(&x[(size_t)(m0+row)*Dz + k0 + c4]);
      As[row][c4] = v.x; As[row][c4+1] = v.y; As[row][c4+2] = v.z; As[row][c4+3] = v.w;
    }
    for (int i = tid; i < PN*(PK/4); i += 256) {
      int row = i >> 3, c4 = (i & 7) << 2;
      float4 v = *reinterpret_cast<const float4*>(&W_ih[(size_t)(n0+row)*(2*Dz) + k0 + c4]);
      Bs[row][c4] = v.x; Bs[row][c4+1] = v.y; Bs[row][c4+2] = v.z; Bs[row][c4+3] = v.w;
    }
    __syncthreads();
    #pragma unroll 8
    for (int k = 0; k < PK; k++) {
      float a8[8], b8[8];
      #pragma unroll
      for (int r = 0; r < 8; r++) a8[r] = As[mg*8+r][k];
      #pragma unroll
      for (int s = 0; s < 8; s++) b8[s] = Bs[ng*8+s][k];
      #pragma unroll
      for (int r = 0; r < 8; r++)
        #pragma unroll
        for (int s = 0; s < 8; s++) acc[r][s] += a8[r]*b8[s];
    }
    __syncthreads();
  }
  #pragma unroll
  for (int r = 0; r < 8; r++) {
    int m = m0 + mg*8 + r;
    #pragma unroll
    for (int s = 0; s < 8; s++) {
      int n = n0 + ng*8 + s;
      xw[(size_t)m*G4D + n] = acc[r][s] + b_ih[n] + b_hh[n];
    }
  }
}

// ---------------- Persistent kernel: f16 payloads, A/B roles ----------------
// A blocks 0..127: (jt = blk>>2 of 64 j, kc = blk&3 of 256 k). W f16 in LDS.
// B blocks 128..159: per-batch reduce+LSTM+GMM+attention; publishes h/ctx as
// packed-f16 k-major arrays hp/cp[256][32].
__global__ __launch_bounds__(512, 1) void k_persist(
    const float* __restrict__ memory, const int* __restrict__ lens,
    const float* __restrict__ W_ih, const float* __restrict__ W_hh,
    const float* __restrict__ W_g,  const float* __restrict__ b_g,
    const float* __restrict__ xw,
    unsigned* __restrict__ hp, unsigned* __restrict__ cp,
    unsigned* __restrict__ part,
    int* __restrict__ flagA, int* __restrict__ flagH, int* __restrict__ flagC,
    float* __restrict__ ctx_out, float* __restrict__ align_out,
    float* __restrict__ term_out)
{
  const int blk = blockIdx.x, tid = threadIdx.x;

  __shared__ __align__(16) char smem[50304];
  __shared__ float phis[3*Mz], prm[3*Mz];
  __shared__ float lom[Mz], him[Mz];
  __shared__ int   rng[2];

  if (blk < NBLKA) {
    // ================= A role =================
    const int jt = blk >> 2, kc = blk & 3;
    const int j0 = jt * JT;
    u64 (*Ws2)[131] = reinterpret_cast<u64(*)[131]>(smem);           // [32][131]
    u64 (*Xs2)[131] = reinterpret_cast<u64(*)[131]>(smem + 33536);   // [16][131]

    // stage W tile once: Ws2[jp][ku] = {f16 pair row 2jp, f16 pair row 2jp+1}
    for (int i = tid; i < 32*KU; i += 512) {
      int jp = i >> 7, ku = i & (KU-1);
      int j = j0 + 2*jp;
      int k = kc*KCH + 2*ku;         // k in [0,1024): [0,512)=ctx, [512,1024)=h
      const float *r0, *r1;
      if (k < 512) { r0 = &W_ih[(size_t)j*(2*Dz) + 512 + k]; r1 = r0 + 2*Dz; }
      else         { r0 = &W_hh[(size_t)j*Dz + (k - 512)];   r1 = r0 + Dz; }
      float2 a = *reinterpret_cast<const float2*>(r0);
      float2 b2 = *reinterpret_cast<const float2*>(r1);
      Ws2[jp][ku] = (u64)pack16(a.x, a.y) | ((u64)pack16(b2.x, b2.y) << 32);
    }

    const unsigned* src = (kc < 2) ? cp : hp;
    const int kub = (kc & 1) * KU;
    const int* wf = (kc >= 2) ? flagH : flagC;

    for (int t = 0; t < Tz; ++t) {
      if (t > 0 && tid < Bz) {
        while (ld_rlx(&wf[tid*FP]) < t) __builtin_amdgcn_s_sleep(1);
      }
      __syncthreads();

      // stage Xs2[bp][ku] = (b-pair, k-pair) from k-major f16 publish arrays
      {
        u64 v[4];
        #pragma unroll
        for (int q = 0; q < 4; q++) {
          int i = (q << 9) + tid;               // 0..2047
          int bp = i >> 7, ku = i & (KU-1);
          v[q] = ld_rlx64(reinterpret_cast<const u64*>(
                     src + (size_t)(kub + ku)*Bz + 2*bp));
        }
        #pragma unroll
        for (int q = 0; q < 4; q++) {
          int i = (q << 9) + tid;
          int bp = i >> 7, ku = i & (KU-1);
          Xs2[bp][ku] = v[q];
        }
      }
      __syncthreads();

      // compute: thread owns 2 j x 2 b, 256 k (128 u64 iters, 4 dot2 each)
      {
        const int jp = tid & 31, bp = tid >> 5;
        float a00 = 0.f, a01 = 0.f, a10 = 0.f, a11 = 0.f;
        #pragma unroll 8
        for (int ku = 0; ku < KU; ku++) {
          u64 w = Ws2[jp][ku];
          u64 xv = Xs2[bp][ku];
          unsigned wlo = (unsigned)w,  whi = (unsigned)(w >> 32);
          unsigned xlo = (unsigned)xv, xhi = (unsigned)(xv >> 32);
          a00 = dot2f(xlo, wlo, a00);   // j0,b0
          a10 = dot2f(xlo, whi, a10);   // j1,b0
          a01 = dot2f(xhi, wlo, a01);   // j0,b1
          a11 = dot2f(xhi, whi, a11);   // j1,b1
        }
        const int ju = jt*32 + jp;
        st_rlxu(part + ((size_t)(kc*Bz + 2*bp)    *1024) + ju, pack16(a00, a10));
        st_rlxu(part + ((size_t)(kc*Bz + 2*bp + 1)*1024) + ju, pack16(a01, a11));
      }
      VWAIT();
      __syncthreads();
      if (tid == 0) st_rlx(&flagA[blk*FP], t+1);
    }
    return;
  }

  // ================= B role =================
  const int b = blk - NBLKA;
  float* gs   = reinterpret_cast<float*>(smem);           // 2048 f (8 KB)
  float* wsm  = reinterpret_cast<float*>(smem + 8192);    // 1024 f
  float* hs   = reinterpret_cast<float*>(smem + 12288);   // 512 f
  float* cs   = reinterpret_cast<float*>(smem + 14336);   // 512 f
  float* ctxl = reinterpret_cast<float*>(smem + 16384);   // 512 f
  float (*part8)[Dz] = reinterpret_cast<float(*)[Dz]>(smem + 18432); // 8x512

  cs[tid] = 0.f;

  for (int t = 0; t < Tz; ++t) {
    // prefetch xw row (independent of A)
    float4 xwv = *reinterpret_cast<const float4*>(&xw[((size_t)b*Tz + t)*G4D + 4*tid]);

    if (tid < NBLKA) {
      while (ld_rlx(&flagA[tid*FP]) < t+1) __builtin_amdgcn_s_sleep(1);
    }
    __syncthreads();

    // gates = xw + 4 f16 partial chunks; thread owns j = 4tid..4tid+3
    {
      float g0 = xwv.x, g1 = xwv.y, g2v = xwv.z, g3 = xwv.w;
      u64 pv[NKC];
      #pragma unroll
      for (int k2 = 0; k2 < NKC; k2++)
        pv[k2] = ld_rlx64(reinterpret_cast<const u64*>(
                     part + ((size_t)(k2*Bz + b)*1024) + 2*tid));
      #pragma unroll
      for (int k2 = 0; k2 < NKC; k2++) {
        half2_t hl = __builtin_bit_cast(half2_t, (unsigned)pv[k2]);
        half2_t hh = __builtin_bit_cast(half2_t, (unsigned)(pv[k2] >> 32));
        g0 += (float)hl[0]; g1 += (float)hl[1];
        g2v += (float)hh[0]; g3 += (float)hh[1];
      }
      *reinterpret_cast<float4*>(&gs[4*tid]) = make_float4(g0, g1, g2v, g3);
    }
    __syncthreads();

    // LSTM pointwise (d = tid), state fp32 in LDS
    {
      const int d = tid;
      float ig = 1.0f/(1.0f+expf(-gs[d]));
      float fg = 1.0f/(1.0f+expf(-gs[Dz+d]));
      float gg = tanhf(gs[2*Dz+d]);
      float og = 1.0f/(1.0f+expf(-gs[3*Dz+d]));
      float cn = fg*cs[d] + ig*gg;
      float hn = og*tanhf(cn);
      cs[d] = cn; hs[d] = hn;
    }
    __syncthreads();
    // publish h as packed f16, k-major hp[u][b]
    if (tid < 256)
      st_rlxu(&hp[(size_t)tid*Bz + b], pack16(hs[2*tid], hs[2*tid+1]));
    VWAIT();
    __syncthreads();
    if (tid == 0) st_rlx(&flagH[b*FP], t+1);   // release h-side A-blocks NOW

    // phi[m] = hs . W_g[m,:] + b_g[m]  (16 lanes/m, float4 rows)
    if (tid < 16*3*Mz) {
      int m = tid >> 4, l16 = tid & 15;
      const float4* wr = reinterpret_cast<const float4*>(W_g + m*Dz);
      const float4* hr = reinterpret_cast<const float4*>(hs);
      float s = 0.f;
      #pragma unroll
      for (int i = 0; i < 8; i++) {
        float4 wv = wr[l16 + (i<<4)];
        float4 hv = hr[l16 + (i<<4)];
        s += wv.x*hv.x + wv.y*hv.y + wv.z*hv.z + wv.w*hv.w;
      }
      s += __shfl_xor(s, 1);
      s += __shfl_xor(s, 2);
      s += __shfl_xor(s, 4);
      s += __shfl_xor(s, 8);
      if (l16 == 0) phis[m] = s + b_g[m];
    }
    __syncthreads();

    // GMM params
    if (tid < Mz) {
      float ks = expf(phis[tid]);
      float be = expf(phis[Mz + tid]);
      prm[tid]      = ks;
      prm[Mz + tid] = expf(-phis[Mz + tid]);   // 1/beta
      lom[tid] = ks - 0.5f - 25.f*be;          // sig(-25) < fp32 visibility
      him[tid] = ks + 0.5f + 25.f*be;
    }
    __syncthreads();
    if (tid == 0) {
      float mx = -1e30f;
      #pragma unroll
      for (int m = 0; m < Mz; m++) mx = fmaxf(mx, phis[2*Mz + m]);
      float ae[Mz], ssum = 0.f;
      #pragma unroll
      for (int m = 0; m < Mz; m++) { ae[m] = expf(phis[2*Mz + m] - mx); ssum += ae[m]; }
      float lo = 1e30f, hi = -1e30f;
      #pragma unroll
      for (int m = 0; m < Mz; m++) {
        prm[2*Mz + m] = ae[m] / ssum;
        lo = fminf(lo, lom[m]); hi = fmaxf(hi, him[m]);
      }
      int llo = lo > 0.f ? (int)floorf(lo) : 0;
      if (llo > Lz) llo = Lz;
      int lhi = hi < (float)Lz ? (int)ceilf(hi) + 1 : Lz;
      if (lhi > Lz) lhi = Lz;
      rng[0] = llo; rng[1] = lhi;
    }
    __syncthreads();
    const int llo = rng[0], lhi = rng[1];

    // w on active range
    for (int l = llo + tid; l < lhi; l += 512) {
      float u = (float)l;
      float t1 = 0.f, t0 = 0.f;
      #pragma unroll
      for (int m = 0; m < Mz; m++) {
        float ks = prm[m], ib = prm[Mz + m], al = prm[2*Mz + m];
        t1 += al * fsig((u + 0.5f - ks) * ib);
        t0 += al * fsig((u - 0.5f - ks) * ib);
      }
      wsm[l] = t1 - t0;
    }
    __syncthreads();

    // ctx einsum: 8 waves split l-range; lane owns 8 consecutive d
    {
      const int wv = tid >> 6, lane = tid & 63, d0 = lane << 3;
      const int range = lhi - llo;
      const int chunk = (range + 7) >> 3;
      const int lbeg = llo + wv*chunk;
      const int lend = (lbeg + chunk < lhi) ? lbeg + chunk : lhi;
      const float* mb = memory + (size_t)b*Lz*Dz + d0;
      float4 a0 = make_float4(0.f,0.f,0.f,0.f), a1 = a0;
      #pragma unroll 2
      for (int l = lbeg; l < lend; l++) {
        float w = wsm[l];
        float4 m0 = *reinterpret_cast<const float4*>(&mb[(size_t)l*Dz]);
        float4 m1 = *reinterpret_cast<const float4*>(&mb[(size_t)l*Dz + 4]);
        a0.x = fmaf(w, m0.x, a0.x); a0.y = fmaf(w, m0.y, a0.y);
        a0.z = fmaf(w, m0.z, a0.z); a0.w = fmaf(w, m0.w, a0.w);
        a1.x = fmaf(w, m1.x, a1.x); a1.y = fmaf(w, m1.y, a1.y);
        a1.z = fmaf(w, m1.z, a1.z); a1.w = fmaf(w, m1.w, a1.w);
      }
      *reinterpret_cast<float4*>(&part8[wv][d0])     = a0;
      *reinterpret_cast<float4*>(&part8[wv][d0 + 4]) = a1;
    }
    __syncthreads();
    {
      const int d = tid;
      float s = part8[0][d] + part8[1][d] + part8[2][d] + part8[3][d]
              + part8[4][d] + part8[5][d] + part8[6][d] + part8[7][d];
      ctxl[d] = s;
      if (t == Tz-1) ctx_out[b*Dz + d] = s;
    }
    __syncthreads();
    // publish ctx as packed f16, k-major cp[u][b]
    if (tid < 256)
      st_rlxu(&cp[(size_t)tid*Bz + b], pack16(ctxl[2*tid], ctxl[2*tid+1]));
    VWAIT();
    __syncthreads();
    if (tid == 0) st_rlx(&flagC[b*FP], t+1);   // release ctx-side A-blocks

    // off critical path: alignment row + termination
    for (int l = llo + tid; l < lhi; l += 512)
      align_out[((size_t)b*Tz + t)*Lz + l] = wsm[l];
    if (t == Tz-1 && tid == 0) {
      float u = (float)(lens[b] - 1);
      float t1 = 0.f;
      #pragma unroll
      for (int m = 0; m < Mz; m++)
        t1 += prm[2*Mz + m] * fsig((u + 0.5f - prm[m]) * prm[Mz + m]);
      term_out[b] = 1.0f - t1;
    }
  }
}

// ================= fallback (small ws): two-kernel loop path =================
__global__ __launch_bounds__(256) void k_gemm(
    const float* __restrict__ x_all, const float* __restrict__ ctxs,
    const float* __restrict__ h, const float* __restrict__ W_ih,
    const float* __restrict__ W_hh, float* __restrict__ partial, int t)
{
  __shared__ float Xs[Bz][130];
  __shared__ float Wt[128][130];
  const int jt = blockIdx.x, kcb = blockIdx.y;
  const int j0 = jt*128, k0 = kcb*128;
  const int tid = threadIdx.x;
  for (int i = tid; i < Bz*128; i += 256) {
    int bb = i >> 7, kk = i & 127;
    int k = k0 + kk;
    float v;
    if (k < Dz)        v = x_all[((size_t)bb*Tz + t)*Dz + k];
    else if (k < 2*Dz) v = ctxs[bb*Dz + (k - Dz)];
    else               v = h[bb*Dz + (k - 2*Dz)];
    Xs[bb][kk] = v;
  }
  {
    const float* Wsrc; int ldw, col0;
    if (k0 < 2*Dz) { Wsrc = W_ih; ldw = 2*Dz; col0 = k0; }
    else           { Wsrc = W_hh; ldw = Dz;   col0 = k0 - 2*Dz; }
    for (int i = tid; i < 128*32; i += 256) {
      int jj = i >> 5, k4 = (i & 31) << 2;
      float4 v = *reinterpret_cast<const float4*>(&Wsrc[(size_t)(j0 + jj)*ldw + col0 + k4]);
      Wt[jj][k4] = v.x; Wt[jj][k4+1] = v.y; Wt[jj][k4+2] = v.z; Wt[jj][k4+3] = v.w;
    }
  }
  __syncthreads();
  const int jg = tid & 31, bg = tid >> 5;
  const int bl = bg << 2;
  float acc[4][4] = {};
  #pragma unroll 4
  for (int k = 0; k < 128; k += 2) {
    float2 xv[4], wv[4];
    #pragma unroll
    for (int b2 = 0; b2 < 4; b2++)
      xv[b2] = *reinterpret_cast<const float2*>(&Xs[bl + b2][k]);
    #pragma unroll
    for (int jj = 0; jj < 4; jj++)
      wv[jj] = *reinterpret_cast<const float2*>(&Wt[jg + (jj << 5)][k]);
    #pragma unroll
    for (int jj = 0; jj < 4; jj++)
      #pragma unroll
      for (int b2 = 0; b2 < 4; b2++)
        acc[jj][b2] += wv[jj].x * xv[b2].x + wv[jj].y * xv[b2].y;
  }
  #pragma unroll
  for (int jj = 0; jj < 4; jj++)
    #pragma unroll
    for (int b2 = 0; b2 < 4; b2++)
      partial[((size_t)kcb*Bz + (bl + b2))*G4D + j0 + jg + (jj << 5)] = acc[jj][b2];
}

__global__ __launch_bounds__(512) void k_fused(
    const float* __restrict__ partial, const float* __restrict__ b_ih,
    const float* __restrict__ b_hh,
    float* __restrict__ h, float* __restrict__ c,
    const float* __restrict__ W_g, const float* __restrict__ b_g,
    const float* __restrict__ memory, const int* __restrict__ lens,
    float* __restrict__ ctxs, float* __restrict__ ctx_out,
    float* __restrict__ align_out, float* __restrict__ term_out,
    int t, int final_, int nkc)
{
  const int b = blockIdx.x, tid = threadIdx.x;
  __shared__ float4 gs4[G4D/4];
  __shared__ float hsb[Dz];
  __shared__ float phis[3*Mz];
  __shared__ float prm[3*Mz];
  __shared__ float wsm[Lz];
  __shared__ int   rng[2];
  float* gs = (float*)gs4;
  {
    int j = 4*tid;
    float4 bi = *reinterpret_cast<const float4*>(&b_ih[j]);
    float4 bh = *reinterpret_cast<const float4*>(&b_hh[j]);
    float4 s = make_float4(bi.x+bh.x, bi.y+bh.y, bi.z+bh.z, bi.w+bh.w);
    const float4* pp = reinterpret_cast<const float4*>(partial) + (size_t)b*(G4D/4) + tid;
    for (int kcb = 0; kcb < nkc; kcb++) {
      float4 p = pp[(size_t)kcb*Bz*(G4D/4)];
      s.x += p.x; s.y += p.y; s.z += p.z; s.w += p.w;
    }
    gs4[tid] = s;
  }
  __syncthreads();
  {
    const int d = tid;
    float ig = 1.0f / (1.0f + expf(-gs[d]));
    float fg = 1.0f / (1.0f + expf(-gs[Dz + d]));
    float gg = tanhf(gs[2*Dz + d]);
    float og = 1.0f / (1.0f + expf(-gs[3*Dz + d]));
    float cn = fg * c[b*Dz + d] + ig * gg;
    float hn = og * tanhf(cn);
    c[b*Dz + d] = cn;
    h[b*Dz + d] = hn;
    hsb[d] = hn;
  }
  __syncthreads();
  if (tid < 16*3*Mz) {
    int m = tid >> 4, l16 = tid & 15;
    float s = 0.f;
    #pragma unroll 4
    for (int k = l16; k < Dz; k += 16) s += W_g[m*Dz + k] * hsb[k];
    s += __shfl_xor(s, 1);
    s += __shfl_xor(s, 2);
    s += __shfl_xor(s, 4);
    s += __shfl_xor(s, 8);
    if (l16 == 0) phis[m] = s + b_g[m];
  }
  __syncthreads();
  if (tid == 0) {
    float mx = -1e30f;
    #pragma unroll
    for (int m = 0; m < Mz; m++) mx = fmaxf(mx, phis[2*Mz + m]);
    float ae[Mz], ssum = 0.f;
    #pragma unroll
    for (int m = 0; m < Mz; m++) { ae[m] = expf(phis[2*Mz + m] - mx); ssum += ae[m]; }
    float lo = 1e30f, hi = -1e30f;
    #pragma unroll
    for (int m = 0; m < Mz; m++) {
      float ks = expf(phis[m]);
      float be = expf(phis[Mz + m]);
      prm[m]        = ks;
      prm[Mz + m]   = expf(-phis[Mz + m]);
      prm[2*Mz + m] = ae[m] / ssum;
      lo = fminf(lo, ks - 0.5f - 25.f*be);
      hi = fmaxf(hi, ks + 0.5f + 25.f*be);
    }
    int llo = lo > 0.f ? (int)floorf(lo) : 0;
    if (llo > Lz) llo = Lz;
    int lhi = hi < (float)Lz ? (int)ceilf(hi) + 1 : Lz;
    if (lhi > Lz) lhi = Lz;
    rng[0] = llo; rng[1] = lhi;
  }
  __syncthreads();
  const int llo = rng[0], lhi = rng[1];
  for (int l = llo + tid; l < lhi; l += 512) {
    float u = (float)l;
    float t1 = 0.f, t0 = 0.f;
    #pragma unroll
    for (int m = 0; m < Mz; m++) {
      float ks = prm[m], ib = prm[Mz + m], al = prm[2*Mz + m];
      t1 += al * fsig((u + 0.5f - ks) * ib);
      t0 += al * fsig((u - 0.5f - ks) * ib);
    }
    float w = t1 - t0;
    wsm[l] = w;
    align_out[((size_t)b*Tz + t)*Lz + l] = w;
  }
  __syncthreads();
  {
    const float* mb = memory + (size_t)b*Lz*Dz + tid;
    float acc = 0.f;
    #pragma unroll 4
    for (int l = llo; l < lhi; l++)
      acc += wsm[l] * mb[(size_t)l*Dz];
    ctxs[b*Dz + tid] = acc;
    if (final_) ctx_out[b*Dz + tid] = acc;
  }
  if (final_ && tid == 0) {
    float u = (float)(lens[b] - 1);
    float t1 = 0.f;
    #pragma unroll
    for (int m = 0; m < Mz; m++)
      t1 += prm[2*Mz + m] * fsig((u + 0.5f - prm[m]) * prm[Mz + m]);
    term_out[b] = 1.0f - t1;
  }
}

extern "C" void kernel_launch(void* const* d_in, const int* in_sizes, int n_in,
                              void* d_out, int out_size, void* d_ws, size_t ws_size,
                              hipStream_t stream)
{
  (void)in_sizes; (void)n_in; (void)out_size;
  const float* x    = (const float*)d_in[0];
  const float* mem  = (const float*)d_in[1];
  const int*   lens = (const int*)d_in[2];
  const float* W_ih = (const float*)d_in[3];
  const float* W_hh = (const float*)d_in[4];
  const float* b_ih = (const float*)d_in[5];
  const float* b_hh = (const float*)d_in[6];
  const float* W_g  = (const float*)d_in[7];
  const float* b_g  = (const float*)d_in[8];

  float* out = (float*)d_out;
  float* ctx_out   = out;                                  // [B,1,D]
  float* align_out = out + Bz*Dz;                          // [B,T,L]
  float* term_out  = out + Bz*Dz + (size_t)Bz*Tz*Lz;       // [B,1]

  const size_t needP = (size_t)OFF_XW*4 + (size_t)Bz*Tz*G4D*sizeof(float);

  hipMemsetAsync(align_out, 0, (size_t)Bz*Tz*Lz*sizeof(float), stream);

  if (ws_size >= needP) {
    int*      ip    = (int*)d_ws;
    int*      flagA = ip + OFF_FLAGA;
    int*      flagH = ip + OFF_FLAGH;
    int*      flagC = ip + OFF_FLAGC;
    unsigned* hp    = (unsigned*)(ip + OFF_HP);
    unsigned* cp    = (unsigned*)(ip + OFF_CP);
    unsigned* part  = (unsigned*)(ip + OFF_PART);
    float*    xw    = (float*)(ip + OFF_XW);

    // zero flags + hp + cp (initial state = 0)
    hipMemsetAsync(d_ws, 0, (size_t)OFF_PART*4, stream);
    k_pre<<<dim3((Bz*Tz)/PM, G4D/PN), 256, 0, stream>>>(x, W_ih, b_ih, b_hh, xw);
    k_persist<<<NBLK, 512, 0, stream>>>(mem, lens, W_ih, W_hh, W_g, b_g, xw,
                                        hp, cp, part, flagA, flagH, flagC,
                                        ctx_out, align_out, term_out);
  } else {
    float* wsf     = (float*)d_ws;
    float* h       = wsf;
    float* c       = h + Bz*Dz;
    float* ctxs    = c + Bz*Dz;
    float* partial = ctxs + Bz*Dz;               // [12][B][4D]
    hipMemsetAsync(d_ws, 0, (size_t)(3*Bz*Dz)*sizeof(float), stream);
    for (int t = 0; t < Tz; t++) {
      k_gemm<<<dim3(G4D/128, 12), 256, 0, stream>>>(x, ctxs, h, W_ih, W_hh, partial, t);
      k_fused<<<Bz, 512, 0, stream>>>(partial, b_ih, b_hh, h, c, W_g, b_g,
                                      mem, lens, ctxs, ctx_out, align_out, term_out,
                                      t, t == Tz-1, 12);
    }
  }
}